// Round 3
// baseline (4195.868 us; speedup 1.0000x reference)
//
#include <hip/hip_runtime.h>

#define BS 4096
#define NV 778
#define NJ 16
#define NC 45

// ws float offsets
#define WS_JRS   0                       // 480 floats: (JR@shapedirs)[j,d,s]
#define WS_JRVT  480                     // 48 floats:  (JR@v_template)[j,d]
#define WS_SE3   528                     // BS*192
#define WS_AT    (528 + BS*192)          // 148*BS, layout [k][b]: k<135 pose-feat,
                                         // 135..144 shape, 145 ones, 146..147 zeros
#define WS_SHIFT (WS_AT + 148*BS)        // BS*4, trans - center

// ---------------- kernel A: batch-independent precompute ----------------
__global__ __launch_bounds__(64) void mano_pre(
    const float* __restrict__ shapedirs, const float* __restrict__ v_template,
    const float* __restrict__ JR, float* __restrict__ ws)
{
    int o = blockIdx.x;          // 0..527
    int lane = threadIdx.x;
    float acc = 0.0f;
    if (o < 480) {
        int j = o / 30, rem = o % 30;
        for (int v = lane; v < NV; v += 64)
            acc += JR[j * NV + v] * shapedirs[v * 30 + rem];
    } else {
        int o2 = o - 480;
        int j = o2 / 3, d = o2 % 3;
        for (int v = lane; v < NV; v += 64)
            acc += JR[j * NV + v] * v_template[v * 3 + d];
    }
    #pragma unroll
    for (int off = 32; off > 0; off >>= 1) acc += __shfl_down(acc, off, 64);
    if (lane == 0) ws[(o < 480) ? (WS_JRS + o) : (WS_JRVT + (o - 480))] = acc;
}

// ---------------- kernel B: per-batch prep (1 wave / batch) ----------------
__global__ __launch_bounds__(64) void mano_batch(
    const float* __restrict__ root_rot, const float* __restrict__ pose,
    const float* __restrict__ shape, const float* __restrict__ trans,
    const float* __restrict__ hc, const float* __restrict__ hmean,
    float* __restrict__ ws, float* __restrict__ out)
{
    const int b = blockIdx.x;
    const int t = threadIdx.x;

    __shared__ float s_pose[NC], s_shape[10], s_axis[NC];
    __shared__ float s_rot[135], s_pf[135];
    __shared__ float s_jt[48], s_A[192], s_SE3[192], s_jl[48], s_shift[3];

    if (t < NC) s_pose[t] = pose[b * NC + t];
    if (t < 10) s_shape[t] = shape[b * 10 + t];
    __syncthreads();

    if (t < NC) {
        float a = hmean[t];
        for (int i = 0; i < NC; ++i) a += s_pose[i] * hc[i * NC + t];
        s_axis[t] = a;
    }
    __syncthreads();

    if (t < 15) {   // Rodrigues
        float ax = s_axis[t*3+0], ay = s_axis[t*3+1], az = s_axis[t*3+2];
        float angle = sqrtf(ax*ax + ay*ay + az*az + 1e-12f);
        float inv = 1.0f / angle;
        float ux = ax*inv, uy = ay*inv, uz = az*inv;
        float c = cosf(angle), s = sinf(angle), ic = 1.0f - c;
        float R[9];
        R[0]=c+ic*ux*ux;       R[1]=-s*uz+ic*ux*uy;  R[2]= s*uy+ic*ux*uz;
        R[3]= s*uz+ic*ux*uy;   R[4]=c+ic*uy*uy;      R[5]=-s*ux+ic*uy*uz;
        R[6]=-s*uy+ic*ux*uz;   R[7]= s*ux+ic*uy*uz;  R[8]=c+ic*uz*uz;
        #pragma unroll
        for (int k = 0; k < 9; ++k) {
            s_rot[t*9+k] = R[k];
            s_pf[t*9+k]  = R[k] - ((k==0||k==4||k==8) ? 1.0f : 0.0f);
        }
    }
    if (t < 48) {   // j_tpose via (JR@shapedirs) trick
        float a = ws[WS_JRVT + t];
        #pragma unroll
        for (int s2 = 0; s2 < 10; ++s2) a += ws[WS_JRS + t*10 + s2] * s_shape[s2];
        s_jt[t] = a;
    }
    __syncthreads();

    if (t < NJ) {   // local [R | j - R j]
        float R[9];
        if (t == 0) {
            #pragma unroll
            for (int k = 0; k < 9; ++k) R[k] = root_rot[b*9+k];
        } else {
            #pragma unroll
            for (int k = 0; k < 9; ++k) R[k] = s_rot[(t-1)*9+k];
        }
        float jx = s_jt[t*3+0], jy = s_jt[t*3+1], jz = s_jt[t*3+2];
        #pragma unroll
        for (int r = 0; r < 3; ++r) {
            float jr = (r==0)?jx:((r==1)?jy:jz);
            float ti = jr - (R[r*3+0]*jx + R[r*3+1]*jy + R[r*3+2]*jz);
            s_A[t*12+r*4+0]=R[r*3+0]; s_A[t*12+r*4+1]=R[r*3+1];
            s_A[t*12+r*4+2]=R[r*3+2]; s_A[t*12+r*4+3]=ti;
        }
    }
    __syncthreads();

    if (t == 5) {
        #pragma unroll
        for (int k = 0; k < 12; ++k) s_SE3[k] = s_A[k];
    }
    if (t < 5) {    // 5 chains of depth 3
        float P[12];
        #pragma unroll
        for (int k = 0; k < 12; ++k) P[k] = s_A[k];
        for (int step = 0; step < 3; ++step) {
            int i = t*3 + 1 + step;
            float M[12];
            #pragma unroll
            for (int r = 0; r < 3; ++r) {
                #pragma unroll
                for (int c = 0; c < 3; ++c)
                    M[r*4+c] = P[r*4+0]*s_A[i*12+0*4+c] + P[r*4+1]*s_A[i*12+1*4+c]
                             + P[r*4+2]*s_A[i*12+2*4+c];
                M[r*4+3] = P[r*4+0]*s_A[i*12+3] + P[r*4+1]*s_A[i*12+7]
                         + P[r*4+2]*s_A[i*12+11] + P[r*4+3];
            }
            #pragma unroll
            for (int k = 0; k < 12; ++k) { s_SE3[i*12+k] = M[k]; P[k] = M[k]; }
        }
    }
    __syncthreads();

    if (t < NJ) {   // posed joints
        if (t == 0) { s_jl[0]=s_jt[0]; s_jl[1]=s_jt[1]; s_jl[2]=s_jt[2]; }
        else {
            const int PAR[NJ] = {-1,0,1,2,0,4,5,0,7,8,0,10,11,0,13,14};
            int p = PAR[t];
            float jx = s_jt[t*3+0], jy = s_jt[t*3+1], jz = s_jt[t*3+2];
            #pragma unroll
            for (int r = 0; r < 3; ++r)
                s_jl[t*3+r] = s_SE3[p*12+r*4+0]*jx + s_SE3[p*12+r*4+1]*jy
                            + s_SE3[p*12+r*4+2]*jz + s_SE3[p*12+r*4+3];
        }
    }
    if (t < 3) s_shift[t] = trans[b*3+t] - s_jt[t];
    __syncthreads();

    // ---- stores ----
    // A-matrix rows [k][b]: pose-feat, shape, ones, zeros
    for (int k = t; k < 148; k += 64) {
        float val;
        if (k < 135)       val = s_pf[k];
        else if (k < 145)  val = s_shape[k - 135];
        else if (k == 145) val = 1.0f;
        else               val = 0.0f;
        ws[WS_AT + k*BS + b] = val;
    }
    for (int k = t; k < 192; k += 64) ws[WS_SE3 + b*192 + k] = s_SE3[k];
    if (t < 4) ws[WS_SHIFT + b*4 + t] = (t < 3) ? s_shift[t] : 0.0f;
    if (t < 21) {
        const int NO[21] = {0,13,14,15,16,1,2,3,17,4,5,6,18,10,11,12,19,7,8,9,20};
        int src = NO[t];
        if (src < 16) {
            size_t jb = (size_t)BS*2334 + (size_t)b*63 + (size_t)t*3;
            out[jb+0] = s_jl[src*3+0] + s_shift[0];
            out[jb+1] = s_jl[src*3+1] + s_shift[1];
            out[jb+2] = s_jl[src*3+2] + s_shift[2];
        }
    }
}

// ---------------- kernel C: GEMM (K=148) + fused LBS ----------------
// Block: 64 batches x 16 vertices. Thread: 4 batches x 1 vertex.
// Everything staged in LDS (compulsory HBM traffic only).
// A staged in TWO K-halves (rows 0..75, 76..147) to shrink LDS -> 3 blocks/CU.
#define AS_ROWS 76
#define AS_LD   72      // row stride (floats)
#define SS_LD   196     // SE3 row stride per batch

__global__ __launch_bounds__(256, 3) void mano_verts(
    const float* __restrict__ posedirs, const float* __restrict__ shapedirs,
    const float* __restrict__ v_template, const float* __restrict__ weights,
    const float* __restrict__ ws, float* __restrict__ out)
{
    const int btile = blockIdx.x;   // 0..63
    const int vtile = blockIdx.y;   // 0..48
    const int t = threadIdx.x;
    const int b0 = btile * 64;
    const int v0 = vtile * 16;

    __shared__ union {
        struct { float As[AS_ROWS*AS_LD]; float Bs[48*148]; } g; // 21888+28416 B
        float Ss[64*SS_LD];                                      // 50176 B
    } u;
    __shared__ float s_w[16*20];    // weights tile, stride 20 (float4-readable)
    __shared__ float s_sh[64*4];    // shift tile

    // ---- stage weights + shift (persist across phases) ----
    {
        int vl = t >> 4, j = t & 15;
        int vg = v0 + vl; if (vg > NV-1) vg = NV-1;
        s_w[vl*20 + j] = weights[vg*16 + j];
    }
    s_sh[t] = ws[WS_SHIFT + b0*4 + t];

    // ---- stage B: [col=48][k=148], vector LDS writes ----
    for (int idx = t; idx < 48*37; idx += 256) {
        int col = idx / 37, kq = idx - col*37;
        int kk = kq * 4;
        int vg = v0 + col/3; if (vg > NV-1) vg = NV-1;
        int d = col % 3;
        float tmp[4];
        #pragma unroll
        for (int uu = 0; uu < 4; ++uu) {
            int k = kk + uu;
            float x;
            if (k < 135)       x = posedirs[vg*405 + d*135 + k];
            else if (k < 145)  x = shapedirs[vg*30 + d*10 + (k-135)];
            else if (k == 145) x = v_template[vg*3 + d];
            else               x = 0.0f;
            tmp[uu] = x;
        }
        *(float4*)&u.g.Bs[col*148 + kk] = make_float4(tmp[0], tmp[1], tmp[2], tmp[3]);
    }

    // ---- stage A half 0: rows 0..75, float4 over batches ----
    const float* At = ws + WS_AT + b0;
    for (int idx = t; idx < AS_ROWS*16; idx += 256) {
        int kr = idx >> 4, j4 = (idx & 15) << 2;
        *(float4*)&u.g.As[kr*AS_LD + j4] = *(const float4*)&At[(size_t)kr*BS + j4];
    }
    __syncthreads();

    // ---- GEMM ----
    const int vi = t & 15, bq = t >> 4;
    const float* Bv = &u.g.Bs[vi*3*148];

    float acc[4][3];
    #pragma unroll
    for (int i = 0; i < 4; ++i)
        #pragma unroll
        for (int c = 0; c < 3; ++c) acc[i][c] = 0.0f;

    // pass 0: kk = 0..72 (19 groups)
    for (int r = 0; r < 19; ++r) {
        const int kk = r * 4;
        float a_[4][4];   // a_[kq][ib]
        #pragma unroll
        for (int kq = 0; kq < 4; ++kq)
            *(float4*)&a_[kq][0] = *(const float4*)&u.g.As[(kk+kq)*AS_LD + bq*4];
        float b_[3][4];   // b_[c][kq]
        #pragma unroll
        for (int c = 0; c < 3; ++c)
            *(float4*)&b_[c][0] = *(const float4*)&Bv[c*148 + kk];
        #pragma unroll
        for (int ib = 0; ib < 4; ++ib)
            #pragma unroll
            for (int c = 0; c < 3; ++c)
                acc[ib][c] += a_[0][ib]*b_[c][0] + a_[1][ib]*b_[c][1]
                            + a_[2][ib]*b_[c][2] + a_[3][ib]*b_[c][3];
    }
    __syncthreads();

    // ---- stage A half 1: rows 76..147 (72 rows) ----
    for (int idx = t; idx < 72*16; idx += 256) {
        int kr = idx >> 4, j4 = (idx & 15) << 2;
        *(float4*)&u.g.As[kr*AS_LD + j4] = *(const float4*)&At[(size_t)(76+kr)*BS + j4];
    }
    __syncthreads();

    // pass 1: kk = 76..144 (18 groups)
    for (int r = 0; r < 18; ++r) {
        const int kk = 76 + r * 4;
        float a_[4][4];
        #pragma unroll
        for (int kq = 0; kq < 4; ++kq)
            *(float4*)&a_[kq][0] = *(const float4*)&u.g.As[(r*4+kq)*AS_LD + bq*4];
        float b_[3][4];
        #pragma unroll
        for (int c = 0; c < 3; ++c)
            *(float4*)&b_[c][0] = *(const float4*)&Bv[c*148 + kk];
        #pragma unroll
        for (int ib = 0; ib < 4; ++ib)
            #pragma unroll
            for (int c = 0; c < 3; ++c)
                acc[ib][c] += a_[0][ib]*b_[c][0] + a_[1][ib]*b_[c][1]
                            + a_[2][ib]*b_[c][2] + a_[3][ib]*b_[c][3];
    }
    __syncthreads();

    // ---- stage SE3 tile into (reused) LDS: Ss[b][SS_LD], float4 copies ----
    // 192 floats = 48 float4s per batch.
    const float* se3w = ws + WS_SE3 + (size_t)b0*192;
    for (int idx = t; idx < 64*48; idx += 256) {
        int b = idx / 48, q4 = (idx - b*48) << 2;
        *(float4*)&u.Ss[b*SS_LD + q4] = *(const float4*)&se3w[b*192 + q4];
    }
    __syncthreads();

    // ---- LBS epilogue ----
    float4 w0 = *(const float4*)&s_w[vi*20 + 0];
    float4 w1 = *(const float4*)&s_w[vi*20 + 4];
    float4 w2 = *(const float4*)&s_w[vi*20 + 8];
    float4 w3 = *(const float4*)&s_w[vi*20 + 12];
    float wj[16] = {w0.x,w0.y,w0.z,w0.w, w1.x,w1.y,w1.z,w1.w,
                    w2.x,w2.y,w2.z,w2.w, w3.x,w3.y,w3.z,w3.w};

    const int vg = v0 + vi;
    const bool vok = (vg < NV);
    int slot = -1;
    if (vg == 745) slot = 4; else if (vg == 333) slot = 8; else if (vg == 444) slot = 12;
    else if (vg == 555) slot = 16; else if (vg == 672) slot = 20;

    #pragma unroll
    for (int ib = 0; ib < 4; ++ib) {
        const int bl = bq*4 + ib;
        const int bg = b0 + bl;
        const float* S = &u.Ss[bl*SS_LD];
        float M[12];
        #pragma unroll
        for (int k = 0; k < 12; ++k) M[k] = 0.0f;
        #pragma unroll
        for (int j = 0; j < 16; ++j) {
            float w = wj[j];
            float4 r0 = *(const float4*)&S[j*12 + 0];
            float4 r1 = *(const float4*)&S[j*12 + 4];
            float4 r2 = *(const float4*)&S[j*12 + 8];
            M[0] += w*r0.x; M[1] += w*r0.y; M[2]  += w*r0.z; M[3]  += w*r0.w;
            M[4] += w*r1.x; M[5] += w*r1.y; M[6]  += w*r1.z; M[7]  += w*r1.w;
            M[8] += w*r2.x; M[9] += w*r2.y; M[10] += w*r2.z; M[11] += w*r2.w;
        }
        float x = acc[ib][0], y = acc[ib][1], z = acc[ib][2];
        float ox = M[0]*x + M[1]*y + M[2] *z + M[3]  + s_sh[bl*4+0];
        float oy = M[4]*x + M[5]*y + M[6] *z + M[7]  + s_sh[bl*4+1];
        float oz = M[8]*x + M[9]*y + M[10]*z + M[11] + s_sh[bl*4+2];
        if (vok) {
            size_t o = (size_t)bg*2334 + (size_t)vg*3;
            out[o+0] = ox; out[o+1] = oy; out[o+2] = oz;
            if (slot >= 0) {
                size_t jb = (size_t)BS*2334 + (size_t)bg*63 + (size_t)slot*3;
                out[jb+0] = ox; out[jb+1] = oy; out[jb+2] = oz;
            }
        }
    }
}

extern "C" void kernel_launch(void* const* d_in, const int* in_sizes, int n_in,
                              void* d_out, int out_size, void* d_ws, size_t ws_size,
                              hipStream_t stream) {
    (void)in_sizes; (void)n_in; (void)ws_size; (void)out_size;
    const float* root_rot   = (const float*)d_in[0];
    const float* pose       = (const float*)d_in[1];
    const float* shape      = (const float*)d_in[2];
    const float* trans      = (const float*)d_in[3];
    const float* hc         = (const float*)d_in[4];
    const float* hmean      = (const float*)d_in[5];
    const float* shapedirs  = (const float*)d_in[6];
    const float* posedirs   = (const float*)d_in[7];
    const float* v_template = (const float*)d_in[8];
    const float* JR         = (const float*)d_in[9];
    const float* weights    = (const float*)d_in[10];
    float* ws  = (float*)d_ws;
    float* out = (float*)d_out;

    mano_pre<<<dim3(528), dim3(64), 0, stream>>>(shapedirs, v_template, JR, ws);
    mano_batch<<<dim3(BS), dim3(64), 0, stream>>>(root_rot, pose, shape, trans,
                                                  hc, hmean, ws, out);
    mano_verts<<<dim3(64, 49), dim3(256), 0, stream>>>(posedirs, shapedirs, v_template,
                                                       weights, ws, out);
}

// Round 4
// 3511.564 us; speedup vs baseline: 1.1949x; 1.1949x over previous
//
#include <hip/hip_runtime.h>

#define BS 4096
#define NV 778
#define NJ 16
#define NC 45

// ws float offsets
#define WS_JRS   0                       // 480 floats: (JR@shapedirs)[j,d,s]
#define WS_JRVT  480                     // 48 floats:  (JR@v_template)[j,d]
#define WS_SE3   528                     // BS*192
#define WS_AT    (528 + BS*192)          // 148*BS, layout [k][b]: k<135 pose-feat,
                                         // 135..144 shape, 145 ones, 146..147 zeros
#define WS_SHIFT (WS_AT + 148*BS)        // BS*4, trans - center

// ---------------- kernel A: batch-independent precompute ----------------
__global__ __launch_bounds__(64) void mano_pre(
    const float* __restrict__ shapedirs, const float* __restrict__ v_template,
    const float* __restrict__ JR, float* __restrict__ ws)
{
    int o = blockIdx.x;          // 0..527
    int lane = threadIdx.x;
    float acc = 0.0f;
    if (o < 480) {
        int j = o / 30, rem = o % 30;
        for (int v = lane; v < NV; v += 64)
            acc += JR[j * NV + v] * shapedirs[v * 30 + rem];
    } else {
        int o2 = o - 480;
        int j = o2 / 3, d = o2 % 3;
        for (int v = lane; v < NV; v += 64)
            acc += JR[j * NV + v] * v_template[v * 3 + d];
    }
    #pragma unroll
    for (int off = 32; off > 0; off >>= 1) acc += __shfl_down(acc, off, 64);
    if (lane == 0) ws[(o < 480) ? (WS_JRS + o) : (WS_JRVT + (o - 480))] = acc;
}

// ---------------- kernel B: per-batch prep (1 wave / batch) ----------------
__global__ __launch_bounds__(64) void mano_batch(
    const float* __restrict__ root_rot, const float* __restrict__ pose,
    const float* __restrict__ shape, const float* __restrict__ trans,
    const float* __restrict__ hc, const float* __restrict__ hmean,
    float* __restrict__ ws, float* __restrict__ out)
{
    const int b = blockIdx.x;
    const int t = threadIdx.x;

    __shared__ float s_pose[NC], s_shape[10], s_axis[NC];
    __shared__ float s_rot[135], s_pf[135];
    __shared__ float s_jt[48], s_A[192], s_SE3[192], s_jl[48], s_shift[3];

    if (t < NC) s_pose[t] = pose[b * NC + t];
    if (t < 10) s_shape[t] = shape[b * 10 + t];
    __syncthreads();

    if (t < NC) {
        float a = hmean[t];
        for (int i = 0; i < NC; ++i) a += s_pose[i] * hc[i * NC + t];
        s_axis[t] = a;
    }
    __syncthreads();

    if (t < 15) {   // Rodrigues
        float ax = s_axis[t*3+0], ay = s_axis[t*3+1], az = s_axis[t*3+2];
        float angle = sqrtf(ax*ax + ay*ay + az*az + 1e-12f);
        float inv = 1.0f / angle;
        float ux = ax*inv, uy = ay*inv, uz = az*inv;
        float c = cosf(angle), s = sinf(angle), ic = 1.0f - c;
        float R[9];
        R[0]=c+ic*ux*ux;       R[1]=-s*uz+ic*ux*uy;  R[2]= s*uy+ic*ux*uz;
        R[3]= s*uz+ic*ux*uy;   R[4]=c+ic*uy*uy;      R[5]=-s*ux+ic*uy*uz;
        R[6]=-s*uy+ic*ux*uz;   R[7]= s*ux+ic*uy*uz;  R[8]=c+ic*uz*uz;
        #pragma unroll
        for (int k = 0; k < 9; ++k) {
            s_rot[t*9+k] = R[k];
            s_pf[t*9+k]  = R[k] - ((k==0||k==4||k==8) ? 1.0f : 0.0f);
        }
    }
    if (t < 48) {   // j_tpose via (JR@shapedirs) trick
        float a = ws[WS_JRVT + t];
        #pragma unroll
        for (int s2 = 0; s2 < 10; ++s2) a += ws[WS_JRS + t*10 + s2] * s_shape[s2];
        s_jt[t] = a;
    }
    __syncthreads();

    if (t < NJ) {   // local [R | j - R j]
        float R[9];
        if (t == 0) {
            #pragma unroll
            for (int k = 0; k < 9; ++k) R[k] = root_rot[b*9+k];
        } else {
            #pragma unroll
            for (int k = 0; k < 9; ++k) R[k] = s_rot[(t-1)*9+k];
        }
        float jx = s_jt[t*3+0], jy = s_jt[t*3+1], jz = s_jt[t*3+2];
        #pragma unroll
        for (int r = 0; r < 3; ++r) {
            float jr = (r==0)?jx:((r==1)?jy:jz);
            float ti = jr - (R[r*3+0]*jx + R[r*3+1]*jy + R[r*3+2]*jz);
            s_A[t*12+r*4+0]=R[r*3+0]; s_A[t*12+r*4+1]=R[r*3+1];
            s_A[t*12+r*4+2]=R[r*3+2]; s_A[t*12+r*4+3]=ti;
        }
    }
    __syncthreads();

    if (t == 5) {
        #pragma unroll
        for (int k = 0; k < 12; ++k) s_SE3[k] = s_A[k];
    }
    if (t < 5) {    // 5 chains of depth 3
        float P[12];
        #pragma unroll
        for (int k = 0; k < 12; ++k) P[k] = s_A[k];
        for (int step = 0; step < 3; ++step) {
            int i = t*3 + 1 + step;
            float M[12];
            #pragma unroll
            for (int r = 0; r < 3; ++r) {
                #pragma unroll
                for (int c = 0; c < 3; ++c)
                    M[r*4+c] = P[r*4+0]*s_A[i*12+0*4+c] + P[r*4+1]*s_A[i*12+1*4+c]
                             + P[r*4+2]*s_A[i*12+2*4+c];
                M[r*4+3] = P[r*4+0]*s_A[i*12+3] + P[r*4+1]*s_A[i*12+7]
                         + P[r*4+2]*s_A[i*12+11] + P[r*4+3];
            }
            #pragma unroll
            for (int k = 0; k < 12; ++k) { s_SE3[i*12+k] = M[k]; P[k] = M[k]; }
        }
    }
    __syncthreads();

    if (t < NJ) {   // posed joints
        if (t == 0) { s_jl[0]=s_jt[0]; s_jl[1]=s_jt[1]; s_jl[2]=s_jt[2]; }
        else {
            const int PAR[NJ] = {-1,0,1,2,0,4,5,0,7,8,0,10,11,0,13,14};
            int p = PAR[t];
            float jx = s_jt[t*3+0], jy = s_jt[t*3+1], jz = s_jt[t*3+2];
            #pragma unroll
            for (int r = 0; r < 3; ++r)
                s_jl[t*3+r] = s_SE3[p*12+r*4+0]*jx + s_SE3[p*12+r*4+1]*jy
                            + s_SE3[p*12+r*4+2]*jz + s_SE3[p*12+r*4+3];
        }
    }
    if (t < 3) s_shift[t] = trans[b*3+t] - s_jt[t];
    __syncthreads();

    // ---- stores ----
    // A-matrix rows [k][b]: pose-feat, shape, ones, zeros
    for (int k = t; k < 148; k += 64) {
        float val;
        if (k < 135)       val = s_pf[k];
        else if (k < 145)  val = s_shape[k - 135];
        else if (k == 145) val = 1.0f;
        else               val = 0.0f;
        ws[WS_AT + k*BS + b] = val;
    }
    for (int k = t; k < 192; k += 64) ws[WS_SE3 + b*192 + k] = s_SE3[k];
    if (t < 4) ws[WS_SHIFT + b*4 + t] = (t < 3) ? s_shift[t] : 0.0f;
    if (t < 21) {
        const int NO[21] = {0,13,14,15,16,1,2,3,17,4,5,6,18,10,11,12,19,7,8,9,20};
        int src = NO[t];
        if (src < 16) {
            size_t jb = (size_t)BS*2334 + (size_t)b*63 + (size_t)t*3;
            out[jb+0] = s_jl[src*3+0] + s_shift[0];
            out[jb+1] = s_jl[src*3+1] + s_shift[1];
            out[jb+2] = s_jl[src*3+2] + s_shift[2];
        }
    }
}

// ---------------- kernel C: GEMM (K=148) + fused LBS ----------------
// Block: 64 batches x 16 vertices. Thread: 4 batches x 1 vertex.
// Everything staged in LDS (compulsory HBM traffic only).
// A staged in TWO K-halves (rows 0..75, 76..147): LDS 52.7 KB -> 3 blocks/CU.
// NOTE: NO min-occupancy arg in __launch_bounds__ — passing one sets
// amdgpu-waves-per-eu, caps VGPRs (64/84 observed) and triggers GB-scale
// scratch spill/fill (round-1/round-3 regressions). LDS alone gives 3 blocks/CU.
#define AS_ROWS 76
#define AS_LD   72      // row stride (floats)
#define SS_LD   196     // SE3 row stride per batch

__global__ __launch_bounds__(256) void mano_verts(
    const float* __restrict__ posedirs, const float* __restrict__ shapedirs,
    const float* __restrict__ v_template, const float* __restrict__ weights,
    const float* __restrict__ ws, float* __restrict__ out)
{
    const int btile = blockIdx.x;   // 0..63
    const int vtile = blockIdx.y;   // 0..48
    const int t = threadIdx.x;
    const int b0 = btile * 64;
    const int v0 = vtile * 16;

    __shared__ union {
        struct { float As[AS_ROWS*AS_LD]; float Bs[48*148]; } g; // 21888+28416 B
        float Ss[64*SS_LD];                                      // 50176 B
    } u;
    __shared__ float s_w[16*20];    // weights tile, stride 20 (float4-readable)
    __shared__ float s_sh[64*4];    // shift tile

    // ---- stage weights + shift (persist across phases) ----
    {
        int vl = t >> 4, j = t & 15;
        int vg = v0 + vl; if (vg > NV-1) vg = NV-1;
        s_w[vl*20 + j] = weights[vg*16 + j];
    }
    s_sh[t] = ws[WS_SHIFT + b0*4 + t];

    // ---- stage B: [col=48][k=148], vector LDS writes ----
    for (int idx = t; idx < 48*37; idx += 256) {
        int col = idx / 37, kq = idx - col*37;
        int kk = kq * 4;
        int vg = v0 + col/3; if (vg > NV-1) vg = NV-1;
        int d = col % 3;
        float tmp[4];
        #pragma unroll
        for (int uu = 0; uu < 4; ++uu) {
            int k = kk + uu;
            float x;
            if (k < 135)       x = posedirs[vg*405 + d*135 + k];
            else if (k < 145)  x = shapedirs[vg*30 + d*10 + (k-135)];
            else if (k == 145) x = v_template[vg*3 + d];
            else               x = 0.0f;
            tmp[uu] = x;
        }
        *(float4*)&u.g.Bs[col*148 + kk] = make_float4(tmp[0], tmp[1], tmp[2], tmp[3]);
    }

    // ---- stage A half 0: rows 0..75, float4 over batches ----
    const float* At = ws + WS_AT + b0;
    for (int idx = t; idx < AS_ROWS*16; idx += 256) {
        int kr = idx >> 4, j4 = (idx & 15) << 2;
        *(float4*)&u.g.As[kr*AS_LD + j4] = *(const float4*)&At[(size_t)kr*BS + j4];
    }
    __syncthreads();

    // ---- GEMM ----
    const int vi = t & 15, bq = t >> 4;
    const float* Bv = &u.g.Bs[vi*3*148];

    float acc[4][3];
    #pragma unroll
    for (int i = 0; i < 4; ++i)
        #pragma unroll
        for (int c = 0; c < 3; ++c) acc[i][c] = 0.0f;

    // pass 0: kk = 0..72 (19 groups)
    for (int r = 0; r < 19; ++r) {
        const int kk = r * 4;
        float a_[4][4];   // a_[kq][ib]
        #pragma unroll
        for (int kq = 0; kq < 4; ++kq)
            *(float4*)&a_[kq][0] = *(const float4*)&u.g.As[(kk+kq)*AS_LD + bq*4];
        float b_[3][4];   // b_[c][kq]
        #pragma unroll
        for (int c = 0; c < 3; ++c)
            *(float4*)&b_[c][0] = *(const float4*)&Bv[c*148 + kk];
        #pragma unroll
        for (int ib = 0; ib < 4; ++ib)
            #pragma unroll
            for (int c = 0; c < 3; ++c)
                acc[ib][c] += a_[0][ib]*b_[c][0] + a_[1][ib]*b_[c][1]
                            + a_[2][ib]*b_[c][2] + a_[3][ib]*b_[c][3];
    }
    __syncthreads();

    // ---- stage A half 1: rows 76..147 (72 rows) ----
    for (int idx = t; idx < 72*16; idx += 256) {
        int kr = idx >> 4, j4 = (idx & 15) << 2;
        *(float4*)&u.g.As[kr*AS_LD + j4] = *(const float4*)&At[(size_t)(76+kr)*BS + j4];
    }
    __syncthreads();

    // pass 1: kk = 76..144 (18 groups)
    for (int r = 0; r < 18; ++r) {
        const int kk = 76 + r * 4;
        float a_[4][4];
        #pragma unroll
        for (int kq = 0; kq < 4; ++kq)
            *(float4*)&a_[kq][0] = *(const float4*)&u.g.As[(r*4+kq)*AS_LD + bq*4];
        float b_[3][4];
        #pragma unroll
        for (int c = 0; c < 3; ++c)
            *(float4*)&b_[c][0] = *(const float4*)&Bv[c*148 + kk];
        #pragma unroll
        for (int ib = 0; ib < 4; ++ib)
            #pragma unroll
            for (int c = 0; c < 3; ++c)
                acc[ib][c] += a_[0][ib]*b_[c][0] + a_[1][ib]*b_[c][1]
                            + a_[2][ib]*b_[c][2] + a_[3][ib]*b_[c][3];
    }
    __syncthreads();

    // ---- stage SE3 tile into (reused) LDS: Ss[b][SS_LD], float4 copies ----
    // 192 floats = 48 float4s per batch.
    const float* se3w = ws + WS_SE3 + (size_t)b0*192;
    for (int idx = t; idx < 64*48; idx += 256) {
        int b = idx / 48, q4 = (idx - b*48) << 2;
        *(float4*)&u.Ss[b*SS_LD + q4] = *(const float4*)&se3w[b*192 + q4];
    }
    __syncthreads();

    // ---- LBS epilogue ----
    float4 w0 = *(const float4*)&s_w[vi*20 + 0];
    float4 w1 = *(const float4*)&s_w[vi*20 + 4];
    float4 w2 = *(const float4*)&s_w[vi*20 + 8];
    float4 w3 = *(const float4*)&s_w[vi*20 + 12];
    float wj[16] = {w0.x,w0.y,w0.z,w0.w, w1.x,w1.y,w1.z,w1.w,
                    w2.x,w2.y,w2.z,w2.w, w3.x,w3.y,w3.z,w3.w};

    const int vg = v0 + vi;
    const bool vok = (vg < NV);
    int slot = -1;
    if (vg == 745) slot = 4; else if (vg == 333) slot = 8; else if (vg == 444) slot = 12;
    else if (vg == 555) slot = 16; else if (vg == 672) slot = 20;

    #pragma unroll
    for (int ib = 0; ib < 4; ++ib) {
        const int bl = bq*4 + ib;
        const int bg = b0 + bl;
        const float* S = &u.Ss[bl*SS_LD];
        float M[12];
        #pragma unroll
        for (int k = 0; k < 12; ++k) M[k] = 0.0f;
        #pragma unroll
        for (int j = 0; j < 16; ++j) {
            float w = wj[j];
            float4 r0 = *(const float4*)&S[j*12 + 0];
            float4 r1 = *(const float4*)&S[j*12 + 4];
            float4 r2 = *(const float4*)&S[j*12 + 8];
            M[0] += w*r0.x; M[1] += w*r0.y; M[2]  += w*r0.z; M[3]  += w*r0.w;
            M[4] += w*r1.x; M[5] += w*r1.y; M[6]  += w*r1.z; M[7]  += w*r1.w;
            M[8] += w*r2.x; M[9] += w*r2.y; M[10] += w*r2.z; M[11] += w*r2.w;
        }
        float x = acc[ib][0], y = acc[ib][1], z = acc[ib][2];
        float ox = M[0]*x + M[1]*y + M[2] *z + M[3]  + s_sh[bl*4+0];
        float oy = M[4]*x + M[5]*y + M[6] *z + M[7]  + s_sh[bl*4+1];
        float oz = M[8]*x + M[9]*y + M[10]*z + M[11] + s_sh[bl*4+2];
        if (vok) {
            size_t o = (size_t)bg*2334 + (size_t)vg*3;
            out[o+0] = ox; out[o+1] = oy; out[o+2] = oz;
            if (slot >= 0) {
                size_t jb = (size_t)BS*2334 + (size_t)bg*63 + (size_t)slot*3;
                out[jb+0] = ox; out[jb+1] = oy; out[jb+2] = oz;
            }
        }
    }
}

extern "C" void kernel_launch(void* const* d_in, const int* in_sizes, int n_in,
                              void* d_out, int out_size, void* d_ws, size_t ws_size,
                              hipStream_t stream) {
    (void)in_sizes; (void)n_in; (void)ws_size; (void)out_size;
    const float* root_rot   = (const float*)d_in[0];
    const float* pose       = (const float*)d_in[1];
    const float* shape      = (const float*)d_in[2];
    const float* trans      = (const float*)d_in[3];
    const float* hc         = (const float*)d_in[4];
    const float* hmean      = (const float*)d_in[5];
    const float* shapedirs  = (const float*)d_in[6];
    const float* posedirs   = (const float*)d_in[7];
    const float* v_template = (const float*)d_in[8];
    const float* JR         = (const float*)d_in[9];
    const float* weights    = (const float*)d_in[10];
    float* ws  = (float*)d_ws;
    float* out = (float*)d_out;

    mano_pre<<<dim3(528), dim3(64), 0, stream>>>(shapedirs, v_template, JR, ws);
    mano_batch<<<dim3(BS), dim3(64), 0, stream>>>(root_rot, pose, shape, trans,
                                                  hc, hmean, ws, out);
    mano_verts<<<dim3(64, 49), dim3(256), 0, stream>>>(posedirs, shapedirs, v_template,
                                                       weights, ws, out);
}

// Round 5
// 205.868 us; speedup vs baseline: 20.3814x; 17.0574x over previous
//
#include <hip/hip_runtime.h>

#define BS 4096
#define NV 778
#define NJ 16
#define NC 45

// ws float offsets
#define WS_JRS   0                       // 480 floats: (JR@shapedirs)[j,d,s]
#define WS_JRVT  480                     // 48 floats:  (JR@v_template)[j,d]
#define WS_SE3   528                     // BS*192
#define WS_AT    (528 + BS*192)          // 148*BS, layout [k][b]: k<135 pose-feat,
                                         // 135..144 shape, 145 ones, 146..147 zeros
#define WS_SHIFT (WS_AT + 148*BS)        // BS*4, trans - center

// ---------------- kernel A: batch-independent precompute ----------------
__global__ __launch_bounds__(64) void mano_pre(
    const float* __restrict__ shapedirs, const float* __restrict__ v_template,
    const float* __restrict__ JR, float* __restrict__ ws)
{
    int o = blockIdx.x;          // 0..527
    int lane = threadIdx.x;
    float acc = 0.0f;
    if (o < 480) {
        int j = o / 30, rem = o % 30;
        for (int v = lane; v < NV; v += 64)
            acc += JR[j * NV + v] * shapedirs[v * 30 + rem];
    } else {
        int o2 = o - 480;
        int j = o2 / 3, d = o2 % 3;
        for (int v = lane; v < NV; v += 64)
            acc += JR[j * NV + v] * v_template[v * 3 + d];
    }
    #pragma unroll
    for (int off = 32; off > 0; off >>= 1) acc += __shfl_down(acc, off, 64);
    if (lane == 0) ws[(o < 480) ? (WS_JRS + o) : (WS_JRVT + (o - 480))] = acc;
}

// ---------------- kernel B: per-batch prep (1 wave / batch) ----------------
__global__ __launch_bounds__(64) void mano_batch(
    const float* __restrict__ root_rot, const float* __restrict__ pose,
    const float* __restrict__ shape, const float* __restrict__ trans,
    const float* __restrict__ hc, const float* __restrict__ hmean,
    float* __restrict__ ws, float* __restrict__ out)
{
    const int b = blockIdx.x;
    const int t = threadIdx.x;

    __shared__ float s_pose[NC], s_shape[10], s_axis[NC];
    __shared__ float s_rot[135], s_pf[135];
    __shared__ float s_jt[48], s_A[192], s_SE3[192], s_jl[48], s_shift[3];

    if (t < NC) s_pose[t] = pose[b * NC + t];
    if (t < 10) s_shape[t] = shape[b * 10 + t];
    __syncthreads();

    if (t < NC) {
        float a = hmean[t];
        for (int i = 0; i < NC; ++i) a += s_pose[i] * hc[i * NC + t];
        s_axis[t] = a;
    }
    __syncthreads();

    if (t < 15) {   // Rodrigues
        float ax = s_axis[t*3+0], ay = s_axis[t*3+1], az = s_axis[t*3+2];
        float angle = sqrtf(ax*ax + ay*ay + az*az + 1e-12f);
        float inv = 1.0f / angle;
        float ux = ax*inv, uy = ay*inv, uz = az*inv;
        float c = cosf(angle), s = sinf(angle), ic = 1.0f - c;
        float R[9];
        R[0]=c+ic*ux*ux;       R[1]=-s*uz+ic*ux*uy;  R[2]= s*uy+ic*ux*uz;
        R[3]= s*uz+ic*ux*uy;   R[4]=c+ic*uy*uy;      R[5]=-s*ux+ic*uy*uz;
        R[6]=-s*uy+ic*ux*uz;   R[7]= s*ux+ic*uy*uz;  R[8]=c+ic*uz*uz;
        #pragma unroll
        for (int k = 0; k < 9; ++k) {
            s_rot[t*9+k] = R[k];
            s_pf[t*9+k]  = R[k] - ((k==0||k==4||k==8) ? 1.0f : 0.0f);
        }
    }
    if (t < 48) {   // j_tpose via (JR@shapedirs) trick
        float a = ws[WS_JRVT + t];
        #pragma unroll
        for (int s2 = 0; s2 < 10; ++s2) a += ws[WS_JRS + t*10 + s2] * s_shape[s2];
        s_jt[t] = a;
    }
    __syncthreads();

    if (t < NJ) {   // local [R | j - R j]
        float R[9];
        if (t == 0) {
            #pragma unroll
            for (int k = 0; k < 9; ++k) R[k] = root_rot[b*9+k];
        } else {
            #pragma unroll
            for (int k = 0; k < 9; ++k) R[k] = s_rot[(t-1)*9+k];
        }
        float jx = s_jt[t*3+0], jy = s_jt[t*3+1], jz = s_jt[t*3+2];
        #pragma unroll
        for (int r = 0; r < 3; ++r) {
            float jr = (r==0)?jx:((r==1)?jy:jz);
            float ti = jr - (R[r*3+0]*jx + R[r*3+1]*jy + R[r*3+2]*jz);
            s_A[t*12+r*4+0]=R[r*3+0]; s_A[t*12+r*4+1]=R[r*3+1];
            s_A[t*12+r*4+2]=R[r*3+2]; s_A[t*12+r*4+3]=ti;
        }
    }
    __syncthreads();

    if (t == 5) {
        #pragma unroll
        for (int k = 0; k < 12; ++k) s_SE3[k] = s_A[k];
    }
    if (t < 5) {    // 5 chains of depth 3
        float P[12];
        #pragma unroll
        for (int k = 0; k < 12; ++k) P[k] = s_A[k];
        for (int step = 0; step < 3; ++step) {
            int i = t*3 + 1 + step;
            float M[12];
            #pragma unroll
            for (int r = 0; r < 3; ++r) {
                #pragma unroll
                for (int c = 0; c < 3; ++c)
                    M[r*4+c] = P[r*4+0]*s_A[i*12+0*4+c] + P[r*4+1]*s_A[i*12+1*4+c]
                             + P[r*4+2]*s_A[i*12+2*4+c];
                M[r*4+3] = P[r*4+0]*s_A[i*12+3] + P[r*4+1]*s_A[i*12+7]
                         + P[r*4+2]*s_A[i*12+11] + P[r*4+3];
            }
            #pragma unroll
            for (int k = 0; k < 12; ++k) { s_SE3[i*12+k] = M[k]; P[k] = M[k]; }
        }
    }
    __syncthreads();

    if (t < NJ) {   // posed joints
        if (t == 0) { s_jl[0]=s_jt[0]; s_jl[1]=s_jt[1]; s_jl[2]=s_jt[2]; }
        else {
            const int PAR[NJ] = {-1,0,1,2,0,4,5,0,7,8,0,10,11,0,13,14};
            int p = PAR[t];
            float jx = s_jt[t*3+0], jy = s_jt[t*3+1], jz = s_jt[t*3+2];
            #pragma unroll
            for (int r = 0; r < 3; ++r)
                s_jl[t*3+r] = s_SE3[p*12+r*4+0]*jx + s_SE3[p*12+r*4+1]*jy
                            + s_SE3[p*12+r*4+2]*jz + s_SE3[p*12+r*4+3];
        }
    }
    if (t < 3) s_shift[t] = trans[b*3+t] - s_jt[t];
    __syncthreads();

    // ---- stores ----
    // A-matrix rows [k][b]: pose-feat, shape, ones, zeros
    for (int k = t; k < 148; k += 64) {
        float val;
        if (k < 135)       val = s_pf[k];
        else if (k < 145)  val = s_shape[k - 135];
        else if (k == 145) val = 1.0f;
        else               val = 0.0f;
        ws[WS_AT + k*BS + b] = val;
    }
    for (int k = t; k < 192; k += 64) ws[WS_SE3 + b*192 + k] = s_SE3[k];
    if (t < 4) ws[WS_SHIFT + b*4 + t] = (t < 3) ? s_shift[t] : 0.0f;
    if (t < 21) {
        const int NO[21] = {0,13,14,15,16,1,2,3,17,4,5,6,18,10,11,12,19,7,8,9,20};
        int src = NO[t];
        if (src < 16) {
            size_t jb = (size_t)BS*2334 + (size_t)b*63 + (size_t)t*3;
            out[jb+0] = s_jl[src*3+0] + s_shift[0];
            out[jb+1] = s_jl[src*3+1] + s_shift[1];
            out[jb+2] = s_jl[src*3+2] + s_shift[2];
        }
    }
}

// ---------------- kernel C: GEMM (K=148) + fused LBS ----------------
// Block: 64 batches x 16 vertices. Thread: 4 batches x 1 vertex.
// Everything staged in LDS (compulsory HBM traffic only).
// A staged in TWO K-halves (rows 0..75, 76..147): LDS 52.7 KB -> 3 blocks/CU.
// NOTE 1: NO min-occupancy arg in __launch_bounds__ — it caps VGPRs and
//   triggers scratch spill (rounds 1/3).
// NOTE 2: '#pragma unroll 1' on the K-pass loops is LOAD-BEARING. At 19/18
//   iterations the compiler fully unrolls, hoists ~530 floats of LDS loads,
//   blows past 256 VGPRs and spills GB-scale scratch (round 4: VGPR=256,
//   7.7 GB traffic, 3.3 ms). Round-0's single 37-iter loop was immune only
//   because 37 exceeded the unroll threshold.
#define AS_ROWS 76
#define AS_LD   72      // row stride (floats)
#define SS_LD   196     // SE3 row stride per batch

__global__ __launch_bounds__(256) void mano_verts(
    const float* __restrict__ posedirs, const float* __restrict__ shapedirs,
    const float* __restrict__ v_template, const float* __restrict__ weights,
    const float* __restrict__ ws, float* __restrict__ out)
{
    const int btile = blockIdx.x;   // 0..63
    const int vtile = blockIdx.y;   // 0..48
    const int t = threadIdx.x;
    const int b0 = btile * 64;
    const int v0 = vtile * 16;

    __shared__ union {
        struct { float As[AS_ROWS*AS_LD]; float Bs[48*148]; } g; // 21888+28416 B
        float Ss[64*SS_LD];                                      // 50176 B
    } u;
    __shared__ float s_w[16*20];    // weights tile, stride 20 (float4-readable)
    __shared__ float s_sh[64*4];    // shift tile

    // ---- stage weights + shift (persist across phases) ----
    {
        int vl = t >> 4, j = t & 15;
        int vg = v0 + vl; if (vg > NV-1) vg = NV-1;
        s_w[vl*20 + j] = weights[vg*16 + j];
    }
    s_sh[t] = ws[WS_SHIFT + b0*4 + t];

    // ---- stage B: [col=48][k=148], vector LDS writes ----
    for (int idx = t; idx < 48*37; idx += 256) {
        int col = idx / 37, kq = idx - col*37;
        int kk = kq * 4;
        int vg = v0 + col/3; if (vg > NV-1) vg = NV-1;
        int d = col % 3;
        float tmp[4];
        #pragma unroll
        for (int uu = 0; uu < 4; ++uu) {
            int k = kk + uu;
            float x;
            if (k < 135)       x = posedirs[vg*405 + d*135 + k];
            else if (k < 145)  x = shapedirs[vg*30 + d*10 + (k-135)];
            else if (k == 145) x = v_template[vg*3 + d];
            else               x = 0.0f;
            tmp[uu] = x;
        }
        *(float4*)&u.g.Bs[col*148 + kk] = make_float4(tmp[0], tmp[1], tmp[2], tmp[3]);
    }

    // ---- stage A half 0: rows 0..75, float4 over batches ----
    const float* At = ws + WS_AT + b0;
    for (int idx = t; idx < AS_ROWS*16; idx += 256) {
        int kr = idx >> 4, j4 = (idx & 15) << 2;
        *(float4*)&u.g.As[kr*AS_LD + j4] = *(const float4*)&At[(size_t)kr*BS + j4];
    }
    __syncthreads();

    // ---- GEMM ----
    const int vi = t & 15, bq = t >> 4;
    const float* Bv = &u.g.Bs[vi*3*148];

    float acc[4][3];
    #pragma unroll
    for (int i = 0; i < 4; ++i)
        #pragma unroll
        for (int c = 0; c < 3; ++c) acc[i][c] = 0.0f;

    // pass 0: kk = 0..72 (19 groups) — keep rolled (see NOTE 2)
    #pragma unroll 1
    for (int r = 0; r < 19; ++r) {
        const int kk = r * 4;
        float a_[4][4];   // a_[kq][ib]
        #pragma unroll
        for (int kq = 0; kq < 4; ++kq)
            *(float4*)&a_[kq][0] = *(const float4*)&u.g.As[(kk+kq)*AS_LD + bq*4];
        float b_[3][4];   // b_[c][kq]
        #pragma unroll
        for (int c = 0; c < 3; ++c)
            *(float4*)&b_[c][0] = *(const float4*)&Bv[c*148 + kk];
        #pragma unroll
        for (int ib = 0; ib < 4; ++ib)
            #pragma unroll
            for (int c = 0; c < 3; ++c)
                acc[ib][c] += a_[0][ib]*b_[c][0] + a_[1][ib]*b_[c][1]
                            + a_[2][ib]*b_[c][2] + a_[3][ib]*b_[c][3];
    }
    __syncthreads();

    // ---- stage A half 1: rows 76..147 (72 rows) ----
    for (int idx = t; idx < 72*16; idx += 256) {
        int kr = idx >> 4, j4 = (idx & 15) << 2;
        *(float4*)&u.g.As[kr*AS_LD + j4] = *(const float4*)&At[(size_t)(76+kr)*BS + j4];
    }
    __syncthreads();

    // pass 1: kk = 76..144 (18 groups) — keep rolled (see NOTE 2)
    #pragma unroll 1
    for (int r = 0; r < 18; ++r) {
        const int kk = 76 + r * 4;
        float a_[4][4];
        #pragma unroll
        for (int kq = 0; kq < 4; ++kq)
            *(float4*)&a_[kq][0] = *(const float4*)&u.g.As[(r*4+kq)*AS_LD + bq*4];
        float b_[3][4];
        #pragma unroll
        for (int c = 0; c < 3; ++c)
            *(float4*)&b_[c][0] = *(const float4*)&Bv[c*148 + kk];
        #pragma unroll
        for (int ib = 0; ib < 4; ++ib)
            #pragma unroll
            for (int c = 0; c < 3; ++c)
                acc[ib][c] += a_[0][ib]*b_[c][0] + a_[1][ib]*b_[c][1]
                            + a_[2][ib]*b_[c][2] + a_[3][ib]*b_[c][3];
    }
    __syncthreads();

    // ---- stage SE3 tile into (reused) LDS: Ss[b][SS_LD], float4 copies ----
    // 192 floats = 48 float4s per batch.
    const float* se3w = ws + WS_SE3 + (size_t)b0*192;
    for (int idx = t; idx < 64*48; idx += 256) {
        int b = idx / 48, q4 = (idx - b*48) << 2;
        *(float4*)&u.Ss[b*SS_LD + q4] = *(const float4*)&se3w[b*192 + q4];
    }
    __syncthreads();

    // ---- LBS epilogue ----
    float4 w0 = *(const float4*)&s_w[vi*20 + 0];
    float4 w1 = *(const float4*)&s_w[vi*20 + 4];
    float4 w2 = *(const float4*)&s_w[vi*20 + 8];
    float4 w3 = *(const float4*)&s_w[vi*20 + 12];
    float wj[16] = {w0.x,w0.y,w0.z,w0.w, w1.x,w1.y,w1.z,w1.w,
                    w2.x,w2.y,w2.z,w2.w, w3.x,w3.y,w3.z,w3.w};

    const int vg = v0 + vi;
    const bool vok = (vg < NV);
    int slot = -1;
    if (vg == 745) slot = 4; else if (vg == 333) slot = 8; else if (vg == 444) slot = 12;
    else if (vg == 555) slot = 16; else if (vg == 672) slot = 20;

    #pragma unroll
    for (int ib = 0; ib < 4; ++ib) {
        const int bl = bq*4 + ib;
        const int bg = b0 + bl;
        const float* S = &u.Ss[bl*SS_LD];
        float M[12];
        #pragma unroll
        for (int k = 0; k < 12; ++k) M[k] = 0.0f;
        #pragma unroll
        for (int j = 0; j < 16; ++j) {
            float w = wj[j];
            float4 r0 = *(const float4*)&S[j*12 + 0];
            float4 r1 = *(const float4*)&S[j*12 + 4];
            float4 r2 = *(const float4*)&S[j*12 + 8];
            M[0] += w*r0.x; M[1] += w*r0.y; M[2]  += w*r0.z; M[3]  += w*r0.w;
            M[4] += w*r1.x; M[5] += w*r1.y; M[6]  += w*r1.z; M[7]  += w*r1.w;
            M[8] += w*r2.x; M[9] += w*r2.y; M[10] += w*r2.z; M[11] += w*r2.w;
        }
        float x = acc[ib][0], y = acc[ib][1], z = acc[ib][2];
        float ox = M[0]*x + M[1]*y + M[2] *z + M[3]  + s_sh[bl*4+0];
        float oy = M[4]*x + M[5]*y + M[6] *z + M[7]  + s_sh[bl*4+1];
        float oz = M[8]*x + M[9]*y + M[10]*z + M[11] + s_sh[bl*4+2];
        if (vok) {
            size_t o = (size_t)bg*2334 + (size_t)vg*3;
            out[o+0] = ox; out[o+1] = oy; out[o+2] = oz;
            if (slot >= 0) {
                size_t jb = (size_t)BS*2334 + (size_t)bg*63 + (size_t)slot*3;
                out[jb+0] = ox; out[jb+1] = oy; out[jb+2] = oz;
            }
        }
    }
}

extern "C" void kernel_launch(void* const* d_in, const int* in_sizes, int n_in,
                              void* d_out, int out_size, void* d_ws, size_t ws_size,
                              hipStream_t stream) {
    (void)in_sizes; (void)n_in; (void)ws_size; (void)out_size;
    const float* root_rot   = (const float*)d_in[0];
    const float* pose       = (const float*)d_in[1];
    const float* shape      = (const float*)d_in[2];
    const float* trans      = (const float*)d_in[3];
    const float* hc         = (const float*)d_in[4];
    const float* hmean      = (const float*)d_in[5];
    const float* shapedirs  = (const float*)d_in[6];
    const float* posedirs   = (const float*)d_in[7];
    const float* v_template = (const float*)d_in[8];
    const float* JR         = (const float*)d_in[9];
    const float* weights    = (const float*)d_in[10];
    float* ws  = (float*)d_ws;
    float* out = (float*)d_out;

    mano_pre<<<dim3(528), dim3(64), 0, stream>>>(shapedirs, v_template, JR, ws);
    mano_batch<<<dim3(BS), dim3(64), 0, stream>>>(root_rot, pose, shape, trans,
                                                  hc, hmean, ws, out);
    mano_verts<<<dim3(64, 49), dim3(256), 0, stream>>>(posedirs, shapedirs, v_template,
                                                       weights, ws, out);
}